// Round 4
// baseline (421.110 us; speedup 1.0000x reference)
//
#include <hip/hip_runtime.h>
#include <stdint.h>

typedef __bf16 bf16_t;
typedef __bf16 bf16x4 __attribute__((ext_vector_type(4)));
typedef __bf16 bf16x8 __attribute__((ext_vector_type(8)));
typedef float  f32x4  __attribute__((ext_vector_type(4)));

typedef __attribute__((address_space(1))) const uint32_t gas_u32;
typedef __attribute__((address_space(3))) uint32_t las_u32;

#define MFMA16(a, b, c) __builtin_amdgcn_mfma_f32_16x16x32_bf16((a), (b), (c), 0, 0, 0)
#define SBARM() asm volatile("s_barrier" ::: "memory")

__device__ __forceinline__ void gl_lds16(const bf16_t* g, bf16_t* l) {
    __builtin_amdgcn_global_load_lds((gas_u32*)g, (las_u32*)l, 16, 0, 0);
}

// ---------------------------------------------------------------------------
// fp32 -> bf16 elementwise cast, 8 elem/thread.
// ---------------------------------------------------------------------------
__global__ __launch_bounds__(256) void castbf(const float* __restrict__ X,
                                              bf16_t* __restrict__ Xb)
{
    size_t i = ((size_t)blockIdx.x * 256 + threadIdx.x) * 8;
    float4 a = *(const float4*)&X[i];
    float4 b = *(const float4*)&X[i + 4];
    bf16x8 o;
    o[0] = (bf16_t)a.x; o[1] = (bf16_t)a.y; o[2] = (bf16_t)a.z; o[3] = (bf16_t)a.w;
    o[4] = (bf16_t)b.x; o[5] = (bf16_t)b.y; o[6] = (bf16_t)b.z; o[7] = (bf16_t)b.w;
    *(bf16x8*)&Xb[i] = o;
}

// ---------------------------------------------------------------------------
// Transpose+cast 1024x1024 fp32 weights -> bf16: O[c][r] = W[r][c].
// ---------------------------------------------------------------------------
__global__ __launch_bounds__(256) void ktrans(
    const float* __restrict__ W0, const float* __restrict__ W1,
    const float* __restrict__ W2, const float* __restrict__ W3,
    bf16_t* __restrict__ WT)
{
    __shared__ float t[64 * 68];
    const int z = blockIdx.z;
    const float* W = (z == 0) ? W0 : (z == 1) ? W1 : (z == 2) ? W2 : W3;
    bf16_t* O = WT + (size_t)z * 1024 * 1024;
    const int r0 = blockIdx.y * 64, c0 = blockIdx.x * 64;
    const int tid = threadIdx.x;
    const int row = tid >> 2, colg = (tid & 3) * 16;
#pragma unroll
    for (int p = 0; p < 4; ++p)
        *(float4*)&t[row * 68 + colg + p * 4] =
            *(const float4*)&W[(size_t)(r0 + row) * 1024 + c0 + colg + p * 4];
    __syncthreads();
    bf16x8 v0, v1;
#pragma unroll
    for (int j = 0; j < 8; ++j) {
        v0[j] = (bf16_t)t[(colg + j) * 68 + row];
        v1[j] = (bf16_t)t[(colg + 8 + j) * 68 + row];
    }
    *(bf16x8*)&O[(size_t)(c0 + row) * 1024 + r0 + colg] = v0;
    *(bf16x8*)&O[(size_t)(c0 + row) * 1024 + r0 + colg + 8] = v1;
}

// ---------------------------------------------------------------------------
// 256x256 tile, BK=64 GEMM (frozen from R2 — control kernel this round).
// ---------------------------------------------------------------------------
template <int CMODE, typename OutT>
__global__ __launch_bounds__(512, 2) void gemm256(
    const bf16_t* __restrict__ A, const bf16_t* __restrict__ Bt,
    const float* __restrict__ b0v, const float* __restrict__ b1v,
    const float* __restrict__ b2v, OutT* __restrict__ C,
    int M, int N, int K)
{
    __shared__ bf16_t lds[2][2][256 * 64];  // [buf][A=0/B=1][row*64 + col]
    const int tid = threadIdx.x;
    const int lane = tid & 63, wave = tid >> 6;
    const int q = lane >> 4, ln = lane & 15;
    const int m0 = blockIdx.x * 256, n0 = blockIdx.y * 256;
    const int wm = (wave >> 2) * 128, wn = (wave & 3) * 64;
    const int NT = K >> 6;

    const bf16_t* Ag = A + (size_t)m0 * K;
    const bf16_t* Bg = Bt + (size_t)n0 * K;

    const bf16_t* gstage[4][2];
    bf16_t* lstage[4][2];
#pragma unroll
    for (int cs = 0; cs < 4; ++cs) {
        const int mat = cs >> 1, half = cs & 1;
#pragma unroll
        for (int r = 0; r < 2; ++r) {
            int idx = r * 512 + tid;
            int ri = idx >> 3;
            int row = mat ? (half * 32 + (ri & 31) + ((ri & ~31) << 1))
                          : (half * 64 + (ri & 63) + ((ri & 64) << 1));
            int gs = (idx & 7) ^ (row & 7);
            gstage[cs][r] = (mat ? Bg : Ag) + (size_t)row * K + gs * 8;
            lstage[cs][r] = &lds[0][mat][row * 64 + (idx & 7) * 8];
        }
    }
    auto stage = [&](int cs, int tt) {
        const int koff = tt << 6;
        const int bsel = (tt & 1) << 15;
#pragma unroll
        for (int r = 0; r < 2; ++r)
            gl_lds16(gstage[cs][r] + koff, lstage[cs][r] + bsel);
    };

    int aoff[2][4][2], boff[2][2][2];
#pragma unroll
    for (int mh = 0; mh < 2; ++mh)
#pragma unroll
        for (int mf = 0; mf < 4; ++mf)
#pragma unroll
            for (int ks = 0; ks < 2; ++ks) {
                int row = wm + (mh * 4 + mf) * 16 + ln;
                int g = ((ks << 2) + q) ^ (row & 7);
                aoff[mh][mf][ks] = row * 64 + g * 8;
            }
#pragma unroll
    for (int nh = 0; nh < 2; ++nh)
#pragma unroll
        for (int nf = 0; nf < 2; ++nf)
#pragma unroll
            for (int ks = 0; ks < 2; ++ks) {
                int row = wn + (nh * 2 + nf) * 16 + ln;
                int g = ((ks << 2) + q) ^ (row & 7);
                boff[nh][nf][ks] = row * 64 + g * 8;
            }
    bf16_t* ldsA = &lds[0][0][0];
    bf16_t* ldsB = &lds[0][1][0];

    bf16x8 aA[4][2], aB[4][2], b0f[2][2], b1f[2][2];
    auto lda = [&](bf16x8 (&d)[4][2], int mh, int cur) {
        const int b = cur << 15;
#pragma unroll
        for (int mf = 0; mf < 4; ++mf)
#pragma unroll
            for (int ks = 0; ks < 2; ++ks)
                d[mf][ks] = *(const bf16x8*)&ldsA[b + aoff[mh][mf][ks]];
    };
    auto ldb = [&](bf16x8 (&d)[2][2], int nh, int cur) {
        const int b = cur << 15;
#pragma unroll
        for (int nf = 0; nf < 2; ++nf)
#pragma unroll
            for (int ks = 0; ks < 2; ++ks)
                d[nf][ks] = *(const bf16x8*)&ldsB[b + boff[nh][nf][ks]];
    };

    f32x4 acc[8][4] = {};
    auto mm = [&](bf16x8 (&a)[4][2], bf16x8 (&b)[2][2], int mh, int nh) {
        __builtin_amdgcn_s_setprio(1);
#pragma unroll
        for (int mf = 0; mf < 4; ++mf)
#pragma unroll
            for (int nf = 0; nf < 2; ++nf)
#pragma unroll
                for (int ks = 0; ks < 2; ++ks)
                    acc[mh * 4 + mf][nh * 2 + nf] =
                        MFMA16(a[mf][ks], b[nf][ks], acc[mh * 4 + mf][nh * 2 + nf]);
        __builtin_amdgcn_s_setprio(0);
    };

    stage(0, 0); stage(2, 0); stage(3, 0); stage(1, 0);
    stage(0, 1); stage(2, 1); stage(3, 1);
    asm volatile("s_waitcnt vmcnt(6)" ::: "memory");
    SBARM();
    lda(aA, 0, 0); ldb(b0f, 0, 0);

    for (int t = 0; t < NT; ++t) {
        const int cur = t & 1, nxt = cur ^ 1;
        ldb(b1f, 1, cur);
        if (t + 1 < NT) stage(1, t + 1);
        mm(aA, b0f, 0, 0);
        SBARM();
        lda(aB, 1, cur);
        if (t + 2 < NT) stage(0, t + 2);
        mm(aA, b1f, 0, 1);
        SBARM();
        if (t + 2 < NT) { stage(2, t + 2); stage(3, t + 2); }
        mm(aB, b0f, 1, 0);
        if (t + 2 < NT) asm volatile("s_waitcnt vmcnt(6)" ::: "memory");
        else            asm volatile("s_waitcnt vmcnt(0)" ::: "memory");
        if (t + 1 < NT) { lda(aA, 0, nxt); ldb(b0f, 0, nxt); }
        mm(aB, b1f, 1, 1);
        SBARM();
    }
    __syncthreads();

    if (CMODE == 0) {
        float* myCf = (float*)&lds[0][0][0] + wave * 1088;
        const int nf0 = n0 + wn;
        const int mfst = m0 + wm;
#pragma unroll
        for (int mt = 0; mt < 8; ++mt) {
#pragma unroll
            for (int nt = 0; nt < 4; ++nt) {
                float bv = b0v[nf0 + nt * 16 + ln];
#pragma unroll
                for (int r = 0; r < 4; ++r)
                    myCf[(q * 4 + r) * 68 + nt * 16 + ln] = acc[mt][nt][r] + bv;
            }
#pragma unroll
            for (int c = 0; c < 4; ++c) {
                int flat = c * 64 + lane;
                int rr = flat >> 4, co = (flat & 15) * 4;
                f32x4 v = *(const f32x4*)&myCf[rr * 68 + co];
                *(f32x4*)&C[(size_t)(mfst + mt * 16 + rr) * N + nf0 + co] = v;
            }
        }
    } else {
        bf16_t* myCs = &lds[0][0][0] + wave * 2304;
        const int n_first = n0 + wn;
        const int t_ = n_first >> 10;
        const int h = (n_first >> 6) & 15;
        const float* bp = (t_ == 0) ? b0v : (t_ == 1) ? b1v : b2v;
        const int m_first = m0 + wm;
        const int bI = m_first >> 12, s0 = m_first & 4095;
        bf16_t* Cp = (bf16_t*)C + (size_t)t_ * 16777216 + (size_t)(bI * 16 + h) * 262144;
#pragma unroll
        for (int p = 0; p < 4; ++p) {
#pragma unroll
            for (int mh2 = 0; mh2 < 2; ++mh2) {
                int mf = p * 2 + mh2;
#pragma unroll
                for (int nt = 0; nt < 4; ++nt) {
                    float bv = bp[(n_first + nt * 16 + ln) & 1023];
#pragma unroll
                    for (int r = 0; r < 4; ++r)
                        myCs[(mh2 * 16 + q * 4 + r) * 72 + nt * 16 + ln] =
                            (bf16_t)(acc[mf][nt][r] + bv);
                }
            }
#pragma unroll
            for (int c = 0; c < 4; ++c) {
                int flat = c * 64 + lane;
                int rr = flat >> 3, co = (flat & 7) * 8;
                bf16x8 v = *(const bf16x8*)&myCs[rr * 72 + co];
                *(bf16x8*)&Cp[(size_t)(s0 + p * 32 + rr) * 64 + co] = v;
            }
            __syncthreads();
        }
    }
}

// ---------------------------------------------------------------------------
// K-side, head-major K/V, fused L2-norm. Kp=relu(Khat*proj^T)+0.1;
// partial KV[f][n] per s-chunk of 512. grid (64 bh, 8), 256 thr.
// P[bh][c][n(65)][f(256)] fp32. n: 0..63=d, 64=Ksum.
// T14 async-split: K rows for subtile st+1 issued into regs during st's
// norm phase; V tile loaded to regs one subtile ahead, ds_write late.
// ---------------------------------------------------------------------------
__global__ __launch_bounds__(256) void kside(
    const bf16_t* __restrict__ Khm, const bf16_t* __restrict__ Vhm,
    const bf16_t* __restrict__ proj, float* __restrict__ P)
{
    __shared__ bf16_t KpT[256 * 72];  // [f][s], wave-private f-slices
    __shared__ bf16_t Vt[80 * 72];    // [n][s], shared
    const int tid = threadIdx.x;
    const int lane = tid & 63, wave = tid >> 6;
    const int q = lane >> 4, ln = lane & 15;
    const int bh = blockIdx.x, c = blockIdx.y;

    const bf16_t* Kh = Khm + (size_t)bh * 262144;
    const bf16_t* Vh = Vhm + (size_t)bh * 262144;
    const bf16_t* pr = proj + (size_t)(bh & 15) * 16384;

    for (int i = tid; i < 16 * 72; i += 256) {
        int rr = i / 72, cc = i % 72;
        Vt[(64 + rr) * 72 + cc] = (rr == 0) ? (bf16_t)1.0f : (bf16_t)0.0f;
    }
    bf16x8 pf[4][2];
#pragma unroll
    for (int nt = 0; nt < 4; ++nt)
#pragma unroll
        for (int ks = 0; ks < 2; ++ks)
            pf[nt][ks] = *(const bf16x8*)&pr[(size_t)(wave * 64 + nt * 16 + ln) * 64 + ks * 32 + q * 8];

    const int s_base = c * 512;
    const int vS = (tid >> 3), vD = (tid & 7) * 8;       // V-stage coords
    // --- preload st=0: K rows (4 mt x 2 frags) + V tile (2 frags) ---
    bf16x8 kr[4][2];
#pragma unroll
    for (int mt = 0; mt < 4; ++mt) {
        const bf16_t* rp = &Kh[(size_t)(s_base + mt * 16 + ln) * 64 + q * 8];
        kr[mt][0] = *(const bf16x8*)rp;
        kr[mt][1] = *(const bf16x8*)(rp + 32);
    }
    bf16x8 vr[2];
    vr[0] = *(const bf16x8*)&Vh[(size_t)(s_base + vS) * 64 + vD];
    vr[1] = *(const bf16x8*)&Vh[(size_t)(s_base + 32 + vS) * 64 + vD];

    f32x4 kv[4][5] = {};
    for (int st = 0; st < 8; ++st) {
        const int sn = s_base + ((st < 7) ? (st + 1) : 7) * 64;
        // phase 1: fused norm + features (64 s x this wave's 64 f)
        f32x4 fa[4][4] = {};
#pragma unroll
        for (int mt = 0; mt < 4; ++mt) {
            bf16x8 a0 = kr[mt][0];
            bf16x8 a1 = kr[mt][1];
            // T14: issue next-subtile K row loads now (used next st)
            const bf16_t* rpn = &Kh[(size_t)(sn + mt * 16 + ln) * 64 + q * 8];
            kr[mt][0] = *(const bf16x8*)rpn;
            kr[mt][1] = *(const bf16x8*)(rpn + 32);
            float f[16], ss = 0.f;
#pragma unroll
            for (int i = 0; i < 8; ++i) { f[i] = (float)a0[i]; f[8 + i] = (float)a1[i]; }
#pragma unroll
            for (int i = 0; i < 16; ++i) ss += f[i] * f[i];
            ss += __shfl_xor(ss, 16, 64);
            ss += __shfl_xor(ss, 32, 64);
            float sc = 1.0f / (sqrtf(ss) + 1e-8f);
            bf16x8 na0, na1;
#pragma unroll
            for (int i = 0; i < 8; ++i) {
                na0[i] = (bf16_t)(f[i] * sc);
                na1[i] = (bf16_t)(f[8 + i] * sc);
            }
#pragma unroll
            for (int nt = 0; nt < 4; ++nt) {
                fa[mt][nt] = MFMA16(na0, pf[nt][0], fa[mt][nt]);
                fa[mt][nt] = MFMA16(na1, pf[nt][1], fa[mt][nt]);
            }
        }
        __syncthreads();  // prev phase2 done reading Vt
#pragma unroll
        for (int mt = 0; mt < 4; ++mt)
#pragma unroll
            for (int nt = 0; nt < 4; ++nt) {
                bf16x4 kp;
#pragma unroll
                for (int r = 0; r < 4; ++r)
                    kp[r] = (bf16_t)(fmaxf(fa[mt][nt][r], 0.0f) + 0.1f);
                *(bf16x4*)&KpT[(wave * 64 + nt * 16 + ln) * 72 + mt * 16 + q * 4] = kp;
            }
        // write V tile transposed from prefetched regs: Vt[d][s]
#pragma unroll
        for (int e = 0; e < 8; ++e) Vt[(vD + e) * 72 + vS] = vr[0][e];
#pragma unroll
        for (int e = 0; e < 8; ++e) Vt[(vD + e) * 72 + 32 + vS] = vr[1][e];
        // T14: issue next-subtile V loads (used next st)
        vr[0] = *(const bf16x8*)&Vh[(size_t)(sn + vS) * 64 + vD];
        vr[1] = *(const bf16x8*)&Vh[(size_t)(sn + 32 + vS) * 64 + vD];
        __syncthreads();
        // phase 2: KV[f][n] += KpT * Vt
#pragma unroll
        for (int ks = 0; ks < 2; ++ks)
#pragma unroll
            for (int mt = 0; mt < 4; ++mt) {
                bf16x8 a = *(const bf16x8*)&KpT[(wave * 64 + mt * 16 + ln) * 72 + ks * 32 + q * 8];
#pragma unroll
                for (int nt = 0; nt < 5; ++nt) {
                    bf16x8 bb = *(const bf16x8*)&Vt[(nt * 16 + ln) * 72 + ks * 32 + q * 8];
                    kv[mt][nt] = MFMA16(a, bb, kv[mt][nt]);
                }
            }
    }
    float* Pp = P + (size_t)(bh * 8 + c) * 65 * 256;
#pragma unroll
    for (int mt = 0; mt < 4; ++mt)
#pragma unroll
        for (int nt = 0; nt < 5; ++nt)
            if (nt < 4 || ln == 0)
                *(f32x4*)&Pp[(size_t)(nt * 16 + ln) * 256 + wave * 64 + mt * 16 + q * 4] = kv[mt][nt];
}

// ---------------------------------------------------------------------------
// Reduce 8 chunk-partials -> KVt[bh][n(80)][f(256)] bf16 (rows 65..79 = 0).
// ---------------------------------------------------------------------------
__global__ __launch_bounds__(256) void kreduce(const float* __restrict__ P, bf16_t* __restrict__ KVt)
{
    size_t i = (size_t)blockIdx.x * 256 + threadIdx.x;
    int f = (int)(i & 255);
    int n = (int)((i >> 8) % 80);
    int bh = (int)(i / (256 * 80));
    float s = 0.f;
    if (n < 65) {
        const float* p = P + (size_t)bh * 8 * 65 * 256 + (size_t)n * 256 + f;
#pragma unroll
        for (int c = 0; c < 8; ++c) s += p[(size_t)c * 65 * 256];
    }
    KVt[i] = (bf16_t)s;
}

// ---------------------------------------------------------------------------
// Q-side, head-major Q, fused norm: Qp=relu(Qhat*proj^T)+0.1;
// out = (Qp*KV)/max(Qp*Ksum,1e-6), written ROW-MAJOR [b*4096+s][h*64+d].
// T14: KVt B-fragments prefetched one ks-step ahead into regs; initial
// batch issued before the Qp store phase (hidden under LDS writes).
// ---------------------------------------------------------------------------
__global__ __launch_bounds__(256) void qside(
    const bf16_t* __restrict__ Qhm, const bf16_t* __restrict__ proj,
    const bf16_t* __restrict__ KVt, bf16_t* __restrict__ attn)
{
    __shared__ bf16_t Qp[128 * 136];  // [s][f-half], wave-private 32-row bands
    const int tid = threadIdx.x;
    const int lane = tid & 63, wave = tid >> 6;
    const int q = lane >> 4, ln = lane & 15;
    const int bh = blockIdx.x, stile = blockIdx.y;
    const int bI = bh >> 4, h = bh & 15;

    const bf16_t* Qh = Qhm + (size_t)bh * 262144 + (size_t)stile * 128 * 64;
    const bf16_t* pr = proj + (size_t)h * 16384;
    const bf16_t* kv = KVt + (size_t)bh * 20480;

    // load 2 A-frags (32 rows/wave) + fused fp32 norm
    bf16x8 na[2][2];
#pragma unroll
    for (int mt = 0; mt < 2; ++mt) {
        const bf16_t* rp = &Qh[(size_t)(wave * 32 + mt * 16 + ln) * 64 + q * 8];
        bf16x8 a0 = *(const bf16x8*)rp;
        bf16x8 a1 = *(const bf16x8*)(rp + 32);
        float f[16], ss = 0.f;
#pragma unroll
        for (int i = 0; i < 8; ++i) { f[i] = (float)a0[i]; f[8 + i] = (float)a1[i]; }
#pragma unroll
        for (int i = 0; i < 16; ++i) ss += f[i] * f[i];
        ss += __shfl_xor(ss, 16, 64);
        ss += __shfl_xor(ss, 32, 64);
        float sc = 1.0f / (sqrtf(ss) + 1e-8f);
#pragma unroll
        for (int i = 0; i < 8; ++i) {
            na[mt][0][i] = (bf16_t)(f[i] * sc);
            na[mt][1][i] = (bf16_t)(f[8 + i] * sc);
        }
    }

    f32x4 oacc[2][5] = {};
#pragma unroll
    for (int fh = 0; fh < 2; ++fh) {
        f32x4 fa[2][8] = {};
#pragma unroll
        for (int ks = 0; ks < 2; ++ks) {
            bf16x8 bb[8];
#pragma unroll
            for (int nt = 0; nt < 8; ++nt)
                bb[nt] = *(const bf16x8*)&pr[(size_t)(fh * 128 + nt * 16 + ln) * 64 + ks * 32 + q * 8];
#pragma unroll
            for (int mt = 0; mt < 2; ++mt)
#pragma unroll
                for (int nt = 0; nt < 8; ++nt)
                    fa[mt][nt] = MFMA16(na[mt][ks], bb[nt], fa[mt][nt]);
        }
        // T14: issue PV ks=0 B-fragments now (overlap Qp stores below)
        bf16x8 kvb[5];
#pragma unroll
        for (int nt = 0; nt < 5; ++nt)
            kvb[nt] = *(const bf16x8*)&kv[(size_t)(nt * 16 + ln) * 256 + fh * 128 + q * 8];
#pragma unroll
        for (int mt = 0; mt < 2; ++mt)
#pragma unroll
            for (int nt = 0; nt < 8; ++nt)
#pragma unroll
                for (int r = 0; r < 4; ++r)
                    Qp[(wave * 32 + mt * 16 + q * 4 + r) * 136 + nt * 16 + ln] =
                        (bf16_t)(fmaxf(fa[mt][nt][r], 0.0f) + 0.1f);
#pragma unroll
        for (int ks = 0; ks < 4; ++ks) {
            // T14: prefetch next ks batch while this ks's MFMAs run
            const int ksn = (ks < 3) ? ks + 1 : 3;
            bf16x8 kvn[5];
#pragma unroll
            for (int nt = 0; nt < 5; ++nt)
                kvn[nt] = *(const bf16x8*)&kv[(size_t)(nt * 16 + ln) * 256 + fh * 128 + ksn * 32 + q * 8];
            bf16x8 aa[2];
#pragma unroll
            for (int mt = 0; mt < 2; ++mt)
                aa[mt] = *(const bf16x8*)&Qp[(wave * 32 + mt * 16 + ln) * 136 + ks * 32 + q * 8];
#pragma unroll
            for (int nt = 0; nt < 5; ++nt)
#pragma unroll
                for (int mt = 0; mt < 2; ++mt)
                    oacc[mt][nt] = MFMA16(aa[mt], kvb[nt], oacc[mt][nt]);
#pragma unroll
            for (int nt = 0; nt < 5; ++nt) kvb[nt] = kvn[nt];
        }
    }
    // row-major attn: [(bI*4096 + stile*128 + sl)*1024 + h*64 + d]
    bf16_t* Ap = attn + ((size_t)(bI * 4096 + stile * 128) * 1024) + h * 64;
#pragma unroll
    for (int mt = 0; mt < 2; ++mt)
#pragma unroll
        for (int r = 0; r < 4; ++r) {
            float nrm = fmaxf(__shfl(oacc[mt][4][r], lane & 48, 64), 1e-6f);
            int sl = wave * 32 + mt * 16 + q * 4 + r;
#pragma unroll
            for (int nt = 0; nt < 4; ++nt)
                Ap[(size_t)sl * 1024 + nt * 16 + ln] = (bf16_t)(oacc[mt][nt][r] / nrm);
        }
}

// ---------------------------------------------------------------------------
extern "C" void kernel_launch(void* const* d_in, const int* in_sizes, int n_in,
                              void* d_out, int out_size, void* d_ws, size_t ws_size,
                              hipStream_t stream)
{
    const float* x = (const float*)d_in[0];
    const float* Wq = (const float*)d_in[1];
    const float* bq = (const float*)d_in[2];
    const float* Wk = (const float*)d_in[3];
    const float* bk = (const float*)d_in[4];
    const float* Wv = (const float*)d_in[5];
    const float* bv = (const float*)d_in[6];
    const float* Wo = (const float*)d_in[7];
    const float* bo = (const float*)d_in[8];
    const float* proj = (const float*)d_in[9];

    char* ws = (char*)d_ws;
    bf16_t* WT = (bf16_t*)(ws);                      //  8 MiB (4x 1024^2)
    bf16_t* projb = (bf16_t*)(ws + (8ull << 20));    //  0.5 MiB
    bf16_t* KVt = (bf16_t*)(ws + (9ull << 20));      //  2.5 MiB
    bf16_t* Q = (bf16_t*)(ws + (12ull << 20));       // 32 MiB \ contiguous
    bf16_t* K = (bf16_t*)(ws + (44ull << 20));       // 32 MiB | QKV slab
    bf16_t* V = (bf16_t*)(ws + (76ull << 20));       // 32 MiB / (attn reuses V)
    bf16_t* xb = (bf16_t*)(ws + (108ull << 20));     // 32 MiB (P reuses, 32.5MB)
    float* P = (float*)xb;                           // xb dead after QKV GEMM
    bf16_t* attn = V;                                // V dead after kside
    float* out = (float*)d_out;

    castbf<<<8192, 256, 0, stream>>>(x, xb);
    castbf<<<128, 256, 0, stream>>>(proj, projb);
    ktrans<<<dim3(16, 16, 4), 256, 0, stream>>>(Wq, Wk, Wv, Wo, WT);
    // fused QKV GEMM: N=3072, head-major vectorized store into Q/K/V slab
    gemm256<2, bf16_t><<<dim3(64, 12), 512, 0, stream>>>(
        xb, WT, bq, bk, bv, Q, 16384, 3072, 1024);
    kside<<<dim3(64, 8), 256, 0, stream>>>(K, V, projb, P);
    kreduce<<<5120, 256, 0, stream>>>(P, KVt);
    qside<<<dim3(64, 32), 256, 0, stream>>>(Q, projb, KVt, attn);
    // final GEMM: A = attn row-major, C = row-major fp32 out
    gemm256<0, float><<<dim3(64, 4), 512, 0, stream>>>(
        attn, WT + 3ull * 1048576, bo, bo, bo, out, 16384, 1024, 1024);
}

// Round 5
// 399.484 us; speedup vs baseline: 1.0541x; 1.0541x over previous
//
#include <hip/hip_runtime.h>
#include <stdint.h>

typedef __bf16 bf16_t;
typedef __bf16 bf16x4 __attribute__((ext_vector_type(4)));
typedef __bf16 bf16x8 __attribute__((ext_vector_type(8)));
typedef float  f32x4  __attribute__((ext_vector_type(4)));
typedef unsigned short u16x8 __attribute__((ext_vector_type(8)));
typedef unsigned int u32;

typedef __attribute__((address_space(1))) const uint32_t gas_u32;
typedef __attribute__((address_space(3))) uint32_t las_u32;

#define MFMA16(a, b, c) __builtin_amdgcn_mfma_f32_16x16x32_bf16((a), (b), (c), 0, 0, 0)
// m201-exact sync: raw builtin barrier (no memory clobber -> no implicit
// vmcnt(0)/lgkmcnt(0) drain), bare counted waitcnt asm.
#define SBAR() __builtin_amdgcn_s_barrier()
#define WAIT_LGKM0() asm volatile("s_waitcnt lgkmcnt(0)")

__device__ __forceinline__ void gl_lds16(const bf16_t* g, bf16_t* l) {
    __builtin_amdgcn_global_load_lds((gas_u32*)g, (las_u32*)l, 16, 0, 0);
}

// ---------------------------------------------------------------------------
// fp32 -> bf16 elementwise cast, 8 elem/thread.
// ---------------------------------------------------------------------------
__global__ __launch_bounds__(256) void castbf(const float* __restrict__ X,
                                              bf16_t* __restrict__ Xb)
{
    size_t i = ((size_t)blockIdx.x * 256 + threadIdx.x) * 8;
    float4 a = *(const float4*)&X[i];
    float4 b = *(const float4*)&X[i + 4];
    bf16x8 o;
    o[0] = (bf16_t)a.x; o[1] = (bf16_t)a.y; o[2] = (bf16_t)a.z; o[3] = (bf16_t)a.w;
    o[4] = (bf16_t)b.x; o[5] = (bf16_t)b.y; o[6] = (bf16_t)b.z; o[7] = (bf16_t)b.w;
    *(bf16x8*)&Xb[i] = o;
}

// ---------------------------------------------------------------------------
// Transpose+cast 1024x1024 fp32 weights -> bf16: O[c][r] = W[r][c].
// ---------------------------------------------------------------------------
__global__ __launch_bounds__(256) void ktrans(
    const float* __restrict__ W0, const float* __restrict__ W1,
    const float* __restrict__ W2, const float* __restrict__ W3,
    bf16_t* __restrict__ WT)
{
    __shared__ float t[64 * 68];
    const int z = blockIdx.z;
    const float* W = (z == 0) ? W0 : (z == 1) ? W1 : (z == 2) ? W2 : W3;
    bf16_t* O = WT + (size_t)z * 1024 * 1024;
    const int r0 = blockIdx.y * 64, c0 = blockIdx.x * 64;
    const int tid = threadIdx.x;
    const int row = tid >> 2, colg = (tid & 3) * 16;
#pragma unroll
    for (int p = 0; p < 4; ++p)
        *(float4*)&t[row * 68 + colg + p * 4] =
            *(const float4*)&W[(size_t)(r0 + row) * 1024 + c0 + colg + p * 4];
    __syncthreads();
    bf16x8 v0, v1;
#pragma unroll
    for (int j = 0; j < 8; ++j) {
        v0[j] = (bf16_t)t[(colg + j) * 68 + row];
        v1[j] = (bf16_t)t[(colg + 8 + j) * 68 + row];
    }
    *(bf16x8*)&O[(size_t)(c0 + row) * 1024 + r0 + colg] = v0;
    *(bf16x8*)&O[(size_t)(c0 + row) * 1024 + r0 + colg + 8] = v1;
}

// ---------------------------------------------------------------------------
// 256x256 tile, BK=64, 8-phase counted-vmcnt GEMM. Reverted to the R1/R2
// version (benched 411 us): no register read-ahead (its vmcnt ledger only
// covers the reading wave's own loads -> cross-wave race). All addressing
// precomputed; vmcnt(6) at P4 = oldest 8 loads = tile t+1's 4 half-tiles.
// ---------------------------------------------------------------------------
template <int CMODE, typename OutT>
__global__ __launch_bounds__(512, 2) void gemm256(
    const bf16_t* __restrict__ A, const bf16_t* __restrict__ Bt,
    const float* __restrict__ b0, const float* __restrict__ b1,
    const float* __restrict__ b2, OutT* __restrict__ C,
    int M, int N, int K)
{
    __shared__ bf16_t lds[2][2][256 * 64];  // [buf][A=0/B=1][row*64 + col]
    const int tid = threadIdx.x;
    const int lane = tid & 63, wave = tid >> 6;
    const int q = lane >> 4, ln = lane & 15;
    const int m0 = blockIdx.x * 256, n0 = blockIdx.y * 256;
    const int wm = (wave >> 2) * 128, wn = (wave & 3) * 64;
    const int NT = K >> 6;

    const bf16_t* Ag = A + (size_t)m0 * K;
    const bf16_t* Bg = Bt + (size_t)n0 * K;

    const bf16_t* gstage[4][2];
    bf16_t* lstage[4][2];
#pragma unroll
    for (int cs = 0; cs < 4; ++cs) {
        const int mat = cs >> 1, half = cs & 1;
#pragma unroll
        for (int r = 0; r < 2; ++r) {
            int idx = r * 512 + tid;
            int ri = idx >> 3;
            int row = mat ? (half * 32 + (ri & 31) + ((ri & ~31) << 1))
                          : (half * 64 + (ri & 63) + ((ri & 64) << 1));
            int gs = (idx & 7) ^ (row & 7);
            gstage[cs][r] = (mat ? Bg : Ag) + (size_t)row * K + gs * 8;
            lstage[cs][r] = &lds[0][mat][row * 64 + (idx & 7) * 8];
        }
    }
    auto stage = [&](int cs, int tt) {
        const int koff = tt << 6;          // K advance (elements)
        const int bsel = (tt & 1) << 15;   // buffer stride = 32768 elem
#pragma unroll
        for (int r = 0; r < 2; ++r)
            gl_lds16(gstage[cs][r] + koff, lstage[cs][r] + bsel);
    };

    int aoff[2][4][2], boff[2][2][2];
#pragma unroll
    for (int mh = 0; mh < 2; ++mh)
#pragma unroll
        for (int mf = 0; mf < 4; ++mf)
#pragma unroll
            for (int ks = 0; ks < 2; ++ks) {
                int row = wm + (mh * 4 + mf) * 16 + ln;
                int g = ((ks << 2) + q) ^ (row & 7);
                aoff[mh][mf][ks] = row * 64 + g * 8;
            }
#pragma unroll
    for (int nh = 0; nh < 2; ++nh)
#pragma unroll
        for (int nf = 0; nf < 2; ++nf)
#pragma unroll
            for (int ks = 0; ks < 2; ++ks) {
                int row = wn + (nh * 2 + nf) * 16 + ln;
                int g = ((ks << 2) + q) ^ (row & 7);
                boff[nh][nf][ks] = row * 64 + g * 8;
            }
    bf16_t* ldsA = &lds[0][0][0];
    bf16_t* ldsB = &lds[0][1][0];

    bf16x8 aL[4][2], bL0[2][2], bL1[2][2];
    auto lda = [&](int mh, int cur) {
        const int b = cur << 15;
#pragma unroll
        for (int mf = 0; mf < 4; ++mf)
#pragma unroll
            for (int ks = 0; ks < 2; ++ks)
                aL[mf][ks] = *(const bf16x8*)&ldsA[b + aoff[mh][mf][ks]];
    };
    auto ldb = [&](bf16x8 (&bL)[2][2], int nh, int cur) {
        const int b = cur << 15;
#pragma unroll
        for (int nf = 0; nf < 2; ++nf)
#pragma unroll
            for (int ks = 0; ks < 2; ++ks)
                bL[nf][ks] = *(const bf16x8*)&ldsB[b + boff[nh][nf][ks]];
    };

    f32x4 acc[8][4] = {};
    auto mm = [&](bf16x8 (&bL)[2][2], int mh, int nh) {
        __builtin_amdgcn_s_setprio(1);
#pragma unroll
        for (int mf = 0; mf < 4; ++mf)
#pragma unroll
            for (int nf = 0; nf < 2; ++nf)
#pragma unroll
                for (int ks = 0; ks < 2; ++ks)
                    acc[mh * 4 + mf][nh * 2 + nf] =
                        MFMA16(aL[mf][ks], bL[nf][ks], acc[mh * 4 + mf][nh * 2 + nf]);
        __builtin_amdgcn_s_setprio(0);
    };

    // prologue: t0 {A0,B0,B1,A1}, t1 {A0,B0,B1}; wait t0 landed (6 left)
    stage(0, 0); stage(2, 0); stage(3, 0); stage(1, 0);
    stage(0, 1); stage(2, 1); stage(3, 1);
    asm volatile("s_waitcnt vmcnt(6)");
    __builtin_amdgcn_sched_barrier(0);
    SBAR();

    for (int t = 0; t < NT; ++t) {
        const int cur = t & 1;
        // P1: read Aalpha + Bh0; prefetch t+1 Abeta (other buf)
        lda(0, cur); ldb(bL0, 0, cur);
        if (t + 1 < NT) stage(1, t + 1);
        SBAR(); WAIT_LGKM0();
        mm(bL0, 0, 0);
        SBAR();
        // P2: read Bh1; prefetch t+2 Aalpha (Aalpha reads done @P1)
        ldb(bL1, 1, cur);
        if (t + 2 < NT) stage(0, t + 2);
        SBAR(); WAIT_LGKM0();
        mm(bL1, 0, 1);
        SBAR();
        // P3: read Abeta; prefetch t+2 Bh0 (Bh0 reads done @P1)
        lda(1, cur);
        if (t + 2 < NT) stage(2, t + 2);
        SBAR(); WAIT_LGKM0();
        mm(bL0, 1, 0);
        SBAR();
        // P4: prefetch t+2 Bh1 (Bh1 reads done @P2); counted drain
        if (t + 2 < NT) stage(3, t + 2);
        SBAR();
        mm(bL1, 1, 1);
        if (t + 2 < NT) asm volatile("s_waitcnt vmcnt(6)");
        else            asm volatile("s_waitcnt vmcnt(0)");
        __builtin_amdgcn_sched_barrier(0);
        SBAR();
    }
    __syncthreads();  // full drain before LDS reuse in epilogue

    if (CMODE == 0) {
        float* myCf = (float*)&lds[0][0][0] + wave * 1088;  // 16x68 f32 / wave
        const int nf0 = n0 + wn;
        const int mfst = m0 + wm;
#pragma unroll
        for (int mt = 0; mt < 8; ++mt) {
#pragma unroll
            for (int nt = 0; nt < 4; ++nt) {
                float bv = b0[nf0 + nt * 16 + ln];
#pragma unroll
                for (int r = 0; r < 4; ++r)
                    myCf[(q * 4 + r) * 68 + nt * 16 + ln] = acc[mt][nt][r] + bv;
            }
#pragma unroll
            for (int c = 0; c < 4; ++c) {
                int flat = c * 64 + lane;
                int rr = flat >> 4, co = (flat & 15) * 4;
                f32x4 v = *(const f32x4*)&myCf[rr * 68 + co];
                *(f32x4*)&C[(size_t)(mfst + mt * 16 + rr) * N + nf0 + co] = v;
            }
        }
    } else {
        // head-major bf16: wave tile = 128 s-rows x 64 d (one head)
        bf16_t* myCs = &lds[0][0][0] + wave * 2304;  // 32x72 bf16 / wave
        const int n_first = n0 + wn;
        const int t_ = n_first >> 10;
        const int h = (n_first >> 6) & 15;
        const float* bp = (t_ == 0) ? b0 : (t_ == 1) ? b1 : b2;
        const int m_first = m0 + wm;
        const int bI = m_first >> 12, s0 = m_first & 4095;
        bf16_t* Cp = (bf16_t*)C + (size_t)t_ * 16777216 + (size_t)(bI * 16 + h) * 262144;
#pragma unroll
        for (int p = 0; p < 4; ++p) {
#pragma unroll
            for (int mh2 = 0; mh2 < 2; ++mh2) {
                int mf = p * 2 + mh2;
#pragma unroll
                for (int nt = 0; nt < 4; ++nt) {
                    float bv = bp[(n_first + nt * 16 + ln) & 1023];
#pragma unroll
                    for (int r = 0; r < 4; ++r)
                        myCs[(mh2 * 16 + q * 4 + r) * 72 + nt * 16 + ln] =
                            (bf16_t)(acc[mf][nt][r] + bv);
                }
            }
#pragma unroll
            for (int c = 0; c < 4; ++c) {
                int flat = c * 64 + lane;
                int rr = flat >> 3, co = (flat & 7) * 8;
                bf16x8 v = *(const bf16x8*)&myCs[rr * 72 + co];
                *(bf16x8*)&Cp[(size_t)(s0 + p * 32 + rr) * 64 + co] = v;
            }
            __syncthreads();
        }
    }
}

// ---------------------------------------------------------------------------
// K-side, head-major K/V, fused L2-norm. Kp=relu(Khat*proj^T)+0.1;
// partial KV[f][n] per s-chunk of 512. grid (64 bh, 8), 256 thr.
// P[bh][c][n(65)][f(256)] fp32. n: 0..63=d, 64=Ksum.
// NEW: shared norm — each wave normalizes only ITS 16 rows of the 64-row
// subtile (was: all 4 waves normalized all 64 rows redundantly, 4x VALU),
// publishes to Kn[64][72] with b128 writes, all waves b128-read A-frags.
// V transpose scatter packs s-pairs -> 8 ds_write_b32 (was 16 ds_write_b16).
// ---------------------------------------------------------------------------
__global__ __launch_bounds__(256) void kside(
    const bf16_t* __restrict__ Khm, const bf16_t* __restrict__ Vhm,
    const bf16_t* __restrict__ proj, float* __restrict__ P)
{
    __shared__ bf16_t Kn[64 * 72];    // normalized K subtile [s][d]
    __shared__ bf16_t KpT[256 * 72];  // [f][s], wave-private f-slices
    __shared__ bf16_t Vt[80 * 72];    // [n][s], shared
    const int tid = threadIdx.x;
    const int lane = tid & 63, wave = tid >> 6;
    const int q = lane >> 4, ln = lane & 15;
    const int bh = blockIdx.x, c = blockIdx.y;

    const bf16_t* Kh = Khm + (size_t)bh * 262144;
    const bf16_t* Vh = Vhm + (size_t)bh * 262144;
    const bf16_t* pr = proj + (size_t)(bh & 15) * 16384;

    for (int i = tid; i < 16 * 72; i += 256) {
        int rr = i / 72, cc = i % 72;
        Vt[(64 + rr) * 72 + cc] = (rr == 0) ? (bf16_t)1.0f : (bf16_t)0.0f;
    }
    bf16x8 pf[4][2];
#pragma unroll
    for (int nt = 0; nt < 4; ++nt)
#pragma unroll
        for (int ks = 0; ks < 2; ++ks)
            pf[nt][ks] = *(const bf16x8*)&pr[(size_t)(wave * 64 + nt * 16 + ln) * 64 + ks * 32 + q * 8];

    f32x4 kv[4][5] = {};
    const int s_base = c * 512;
    const int s2 = tid >> 3, vD = (tid & 7) * 8;  // V-stage: s-pair 2*s2, d0
    for (int st = 0; st < 8; ++st) {
        const int s0 = s_base + st * 64;
        // --- norm: this wave's 16 rows only ---
        {
            const bf16_t* rp = &Kh[(size_t)(s0 + wave * 16 + ln) * 64 + q * 8];
            bf16x8 a0 = *(const bf16x8*)rp;
            bf16x8 a1 = *(const bf16x8*)(rp + 32);
            float f[16], ss = 0.f;
#pragma unroll
            for (int i = 0; i < 8; ++i) { f[i] = (float)a0[i]; f[8 + i] = (float)a1[i]; }
#pragma unroll
            for (int i = 0; i < 16; ++i) ss += f[i] * f[i];
            ss += __shfl_xor(ss, 16, 64);
            ss += __shfl_xor(ss, 32, 64);
            float sc = 1.0f / (sqrtf(ss) + 1e-8f);
            bf16x8 na0, na1;
#pragma unroll
            for (int i = 0; i < 8; ++i) {
                na0[i] = (bf16_t)(f[i] * sc);
                na1[i] = (bf16_t)(f[8 + i] * sc);
            }
            *(bf16x8*)&Kn[(wave * 16 + ln) * 72 + q * 8] = na0;
            *(bf16x8*)&Kn[(wave * 16 + ln) * 72 + 32 + q * 8] = na1;
        }
        __syncthreads();  // Kn ready (prev phase2 reads KpT/Vt, no Kn conflict)
        // --- feature GEMM: read Kn A-frags, 32 MFMA ---
        f32x4 fa[4][4] = {};
#pragma unroll
        for (int mt = 0; mt < 4; ++mt) {
            bf16x8 n0v = *(const bf16x8*)&Kn[(mt * 16 + ln) * 72 + q * 8];
            bf16x8 n1v = *(const bf16x8*)&Kn[(mt * 16 + ln) * 72 + 32 + q * 8];
#pragma unroll
            for (int nt = 0; nt < 4; ++nt) {
                fa[mt][nt] = MFMA16(n0v, pf[nt][0], fa[mt][nt]);
                fa[mt][nt] = MFMA16(n1v, pf[nt][1], fa[mt][nt]);
            }
        }
        __syncthreads();  // prev phase2 done reading KpT/Vt
#pragma unroll
        for (int mt = 0; mt < 4; ++mt)
#pragma unroll
            for (int nt = 0; nt < 4; ++nt) {
                bf16x4 kp;
#pragma unroll
                for (int r = 0; r < 4; ++r)
                    kp[r] = (bf16_t)(fmaxf(fa[mt][nt][r], 0.0f) + 0.1f);
                *(bf16x4*)&KpT[(wave * 64 + nt * 16 + ln) * 72 + mt * 16 + q * 4] = kp;
            }
        // stage V tile transposed, s-pairs packed as b32: Vt[d][s]
        {
            u16x8 v0 = *(const u16x8*)&Vh[(size_t)(s0 + 2 * s2) * 64 + vD];
            u16x8 v1 = *(const u16x8*)&Vh[(size_t)(s0 + 2 * s2 + 1) * 64 + vD];
#pragma unroll
            for (int e = 0; e < 8; ++e) {
                u32 w = (u32)v0[e] | ((u32)v1[e] << 16);
                *(u32*)&Vt[(vD + e) * 72 + 2 * s2] = w;
            }
        }
        __syncthreads();
        // phase 2: KV[f][n] += KpT * Vt
#pragma unroll
        for (int ks = 0; ks < 2; ++ks)
#pragma unroll
            for (int mt = 0; mt < 4; ++mt) {
                bf16x8 a = *(const bf16x8*)&KpT[(wave * 64 + mt * 16 + ln) * 72 + ks * 32 + q * 8];
#pragma unroll
                for (int nt = 0; nt < 5; ++nt) {
                    bf16x8 bb = *(const bf16x8*)&Vt[(nt * 16 + ln) * 72 + ks * 32 + q * 8];
                    kv[mt][nt] = MFMA16(a, bb, kv[mt][nt]);
                }
            }
    }
    float* Pp = P + (size_t)(bh * 8 + c) * 65 * 256;
#pragma unroll
    for (int mt = 0; mt < 4; ++mt)
#pragma unroll
        for (int nt = 0; nt < 5; ++nt)
            if (nt < 4 || ln == 0)
                *(f32x4*)&Pp[(size_t)(nt * 16 + ln) * 256 + wave * 64 + mt * 16 + q * 4] = kv[mt][nt];
}

// ---------------------------------------------------------------------------
// Reduce 8 chunk-partials -> KVt[bh][n(80)][f(256)] bf16 (rows 65..79 = 0).
// ---------------------------------------------------------------------------
__global__ __launch_bounds__(256) void kreduce(const float* __restrict__ P, bf16_t* __restrict__ KVt)
{
    size_t i = (size_t)blockIdx.x * 256 + threadIdx.x;
    int f = (int)(i & 255);
    int n = (int)((i >> 8) % 80);
    int bh = (int)(i / (256 * 80));
    float s = 0.f;
    if (n < 65) {
        const float* p = P + (size_t)bh * 8 * 65 * 256 + (size_t)n * 256 + f;
#pragma unroll
        for (int c = 0; c < 8; ++c) s += p[(size_t)c * 65 * 256];
    }
    KVt[i] = (bf16_t)s;
}

// ---------------------------------------------------------------------------
// Q-side, head-major Q, fused norm: Qp=relu(Qhat*proj^T)+0.1;
// out = (Qp*KV)/max(Qp*Ksum,1e-6), written ROW-MAJOR [b*4096+s][h*64+d].
// (reverted to pre-T14 form)
// ---------------------------------------------------------------------------
__global__ __launch_bounds__(256) void qside(
    const bf16_t* __restrict__ Qhm, const bf16_t* __restrict__ proj,
    const bf16_t* __restrict__ KVt, bf16_t* __restrict__ attn)
{
    __shared__ bf16_t Qp[128 * 136];  // [s][f-half], wave-private 32-row bands
    const int tid = threadIdx.x;
    const int lane = tid & 63, wave = tid >> 6;
    const int q = lane >> 4, ln = lane & 15;
    const int bh = blockIdx.x, stile = blockIdx.y;
    const int bI = bh >> 4, h = bh & 15;

    const bf16_t* Qh = Qhm + (size_t)bh * 262144 + (size_t)stile * 128 * 64;
    const bf16_t* pr = proj + (size_t)h * 16384;
    const bf16_t* kv = KVt + (size_t)bh * 20480;

    // load 2 A-frags (32 rows/wave) + fused fp32 norm
    bf16x8 na[2][2];
#pragma unroll
    for (int mt = 0; mt < 2; ++mt) {
        const bf16_t* rp = &Qh[(size_t)(wave * 32 + mt * 16 + ln) * 64 + q * 8];
        bf16x8 a0 = *(const bf16x8*)rp;
        bf16x8 a1 = *(const bf16x8*)(rp + 32);
        float f[16], ss = 0.f;
#pragma unroll
        for (int i = 0; i < 8; ++i) { f[i] = (float)a0[i]; f[8 + i] = (float)a1[i]; }
#pragma unroll
        for (int i = 0; i < 16; ++i) ss += f[i] * f[i];
        ss += __shfl_xor(ss, 16, 64);
        ss += __shfl_xor(ss, 32, 64);
        float sc = 1.0f / (sqrtf(ss) + 1e-8f);
#pragma unroll
        for (int i = 0; i < 8; ++i) {
            na[mt][0][i] = (bf16_t)(f[i] * sc);
            na[mt][1][i] = (bf16_t)(f[8 + i] * sc);
        }
    }

    f32x4 oacc[2][5] = {};
#pragma unroll
    for (int fh = 0; fh < 2; ++fh) {
        f32x4 fa[2][8] = {};
#pragma unroll
        for (int ks = 0; ks < 2; ++ks) {
            bf16x8 bb[8];
#pragma unroll
            for (int nt = 0; nt < 8; ++nt)
                bb[nt] = *(const bf16x8*)&pr[(size_t)(fh * 128 + nt * 16 + ln) * 64 + ks * 32 + q * 8];
#pragma unroll
            for (int mt = 0; mt < 2; ++mt)
#pragma unroll
                for (int nt = 0; nt < 8; ++nt)
                    fa[mt][nt] = MFMA16(na[mt][ks], bb[nt], fa[mt][nt]);
        }
#pragma unroll
        for (int mt = 0; mt < 2; ++mt)
#pragma unroll
            for (int nt = 0; nt < 8; ++nt)
#pragma unroll
                for (int r = 0; r < 4; ++r)
                    Qp[(wave * 32 + mt * 16 + q * 4 + r) * 136 + nt * 16 + ln] =
                        (bf16_t)(fmaxf(fa[mt][nt][r], 0.0f) + 0.1f);
#pragma unroll
        for (int ks = 0; ks < 4; ++ks) {
            bf16x8 aa[2];
#pragma unroll
            for (int mt = 0; mt < 2; ++mt)
                aa[mt] = *(const bf16x8*)&Qp[(wave * 32 + mt * 16 + ln) * 136 + ks * 32 + q * 8];
#pragma unroll
            for (int nt = 0; nt < 5; ++nt) {
                bf16x8 bb = *(const bf16x8*)&kv[(size_t)(nt * 16 + ln) * 256 + fh * 128 + ks * 32 + q * 8];
#pragma unroll
                for (int mt = 0; mt < 2; ++mt)
                    oacc[mt][nt] = MFMA16(aa[mt], bb, oacc[mt][nt]);
            }
        }
    }
    // row-major attn: [(bI*4096 + stile*128 + sl)*1024 + h*64 + d]
    bf16_t* Ap = attn + ((size_t)(bI * 4096 + stile * 128) * 1024) + h * 64;
#pragma unroll
    for (int mt = 0; mt < 2; ++mt)
#pragma unroll
        for (int r = 0; r < 4; ++r) {
            float nrm = fmaxf(__shfl(oacc[mt][4][r], lane & 48, 64), 1e-6f);
            int sl = wave * 32 + mt * 16 + q * 4 + r;
#pragma unroll
            for (int nt = 0; nt < 4; ++nt)
                Ap[(size_t)sl * 1024 + nt * 16 + ln] = (bf16_t)(oacc[mt][nt][r] / nrm);
        }
}

// ---------------------------------------------------------------------------
extern "C" void kernel_launch(void* const* d_in, const int* in_sizes, int n_in,
                              void* d_out, int out_size, void* d_ws, size_t ws_size,
                              hipStream_t stream)
{
    const float* x = (const float*)d_in[0];
    const float* Wq = (const float*)d_in[1];
    const float* bq = (const float*)d_in[2];
    const float* Wk = (const float*)d_in[3];
    const float* bk = (const float*)d_in[4];
    const float* Wv = (const float*)d_in[5];
    const float* bv = (const float*)d_in[6];
    const float* Wo = (const float*)d_in[7];
    const float* bo = (const float*)d_in[8];
    const float* proj = (const float*)d_in[9];

    char* ws = (char*)d_ws;
    bf16_t* WT = (bf16_t*)(ws);                      //  8 MiB (4x 1024^2)
    bf16_t* projb = (bf16_t*)(ws + (8ull << 20));    //  0.5 MiB
    bf16_t* KVt = (bf16_t*)(ws + (9ull << 20));      //  2.5 MiB
    bf16_t* Q = (bf16_t*)(ws + (12ull << 20));       // 32 MiB \ contiguous
    bf16_t* K = (bf16_t*)(ws + (44ull << 20));       // 32 MiB | QKV slab
    bf16_t* V = (bf16_t*)(ws + (76ull << 20));       // 32 MiB / (attn reuses V)
    bf16_t* xb = (bf16_t*)(ws + (108ull << 20));     // 32 MiB (P reuses, 32.5MB)
    float* P = (float*)xb;                           // xb dead after QKV GEMM
    bf16_t* attn = V;                                // V dead after kside
    float* out = (float*)d_out;

    castbf<<<8192, 256, 0, stream>>>(x, xb);
    castbf<<<128, 256, 0, stream>>>(proj, projb);
    ktrans<<<dim3(16, 16, 4), 256, 0, stream>>>(Wq, Wk, Wv, Wo, WT);
    // fused QKV GEMM: N=3072, head-major vectorized store into Q/K/V slab
    gemm256<2, bf16_t><<<dim3(64, 12), 512, 0, stream>>>(
        xb, WT, bq, bk, bv, Q, 16384, 3072, 1024);
    kside<<<dim3(64, 8), 256, 0, stream>>>(K, V, projb, P);
    kreduce<<<5120, 256, 0, stream>>>(P, KVt);
    qside<<<dim3(64, 32), 256, 0, stream>>>(Q, projb, KVt, attn);
    // final GEMM: A = attn row-major, C = row-major fp32 out
    gemm256<0, float><<<dim3(64, 4), 512, 0, stream>>>(
        attn, WT + 3ull * 1048576, bo, bo, bo, out, 16384, 1024, 1024);
}